// Round 2
// baseline (2153.284 us; speedup 1.0000x reference)
//
#include <hip/hip_runtime.h>

typedef unsigned short u16;
typedef unsigned int u32;
typedef unsigned long long u64;
typedef __attribute__((ext_vector_type(8))) short short8;    // 8 bf16 = 4 VGPRs (MFMA A/B frag)
typedef __attribute__((ext_vector_type(4))) float float4_;   // MFMA C/D frag
typedef __attribute__((ext_vector_type(4))) u16 ushort4_;    // 8B vector of bf16
typedef __attribute__((ext_vector_type(4))) u32 uint4_;
typedef __attribute__((ext_vector_type(2))) u32 uint2_;

#define SB 16384   // S*B
#define HH 512     // H
#define NC 21      // C+1

// ws layout (bytes). All offsets 16B-aligned.
// hbuf2: tagged h exchange: [dir][parity][b=64][g=64][32B rec]  (2*2*64*2048 = 524288)
//   record g (owns h[g*8..g*8+7]): bytes 0-15: [e0,e1,e2,tag][e3,e4,e5,tag]
//                                  bytes 16-23: [e6,e7,pad,tag], bytes 24-31 pad.
#define OFF_HBUF 0u          // tagged h dbuf                        (524288)
#define OFF_BIAS 524288u     // bias_n: [dir][4][512] f32            (16384)  -> 540672
#define OFF_LINB 540672u     // linb_n: 21 f32 (+pad)                (256)    -> 540928
#define OFF_LINW 540928u     // linw_n: [21][1024] bf16              (43008)  -> 583936
#define OFF_WHH  583936u     // whh_n: [dir*1536+row][512] bf16      (3145728)-> 3729664
#define OFF_XS   3729664u    // xs2 frag-packed: [s][4][10][512] bf16(10485760)->14215424
#define OFF_WP   14215424u   // wp2 frag-packed: [192][10][512] bf16 (1966080)->16181504
#define OFF_HS   16181504u   // hs: [dir][SB][512] bf16              (33554432)->49735936
#define WS_NEED  49735936u

__device__ __forceinline__ float b2f(u16 u) {
  union { u32 i; float f; } x; x.i = ((u32)u) << 16; return x.f;
}
__device__ __forceinline__ u16 f2b(float f) {  // RNE f32->bf16
  union { float f; u32 i; } x; x.f = f;
  u32 r = x.i + 0x7fffu + ((x.i >> 16) & 1u);
  return (u16)(r >> 16);
}
__device__ __forceinline__ float sigm(float x) { return 1.f / (1.f + __expf(-x)); }
__device__ __forceinline__ float tanh_f(float x) {
  x = fminf(fmaxf(x, -15.f), 15.f);
  float e = __expf(2.f * x);
  return (e - 1.f) / (e + 1.f);
}

// Runtime storage-dtype probe (kept from R6; cheap, in-bounds either way).
__device__ __forceinline__ bool detect_f32(const void* emb) {
  u16 v = ((const u16*)emb)[threadIdx.x & 63];
  int e = (v >> 7) & 0xff;
  return __ballot(e >= 147) != 0ull;
}
__device__ __forceinline__ float rdf(const void* p, size_t i, bool f32m) {
  return f32m ? ((const float*)p)[i] : b2f(((const u16*)p)[i]);
}

__global__ __launch_bounds__(256) void fallback_kernel(float* out, int n, float v) {
  int i = blockIdx.x * 256 + threadIdx.x;
  if (i < n) out[i] = v;
}

// ---------------- normalize everything into canonical ws buffers (unchanged) ----------
__global__ __launch_bounds__(256) void prep_kernel(
    const int* __restrict__ idx, const void* __restrict__ emb,
    const void* __restrict__ wih_f, const void* __restrict__ wih_b,
    const void* __restrict__ whh_f, const void* __restrict__ whh_b,
    const void* __restrict__ bih_f, const void* __restrict__ bih_b,
    const void* __restrict__ bhh_f, const void* __restrict__ bhh_b,
    const void* __restrict__ linW, const void* __restrict__ linb,
    u16* __restrict__ xs2, u16* __restrict__ wp2, u16* __restrict__ whh_n,
    u16* __restrict__ linw_n, float* __restrict__ bias_n, float* __restrict__ linb_n) {
  bool f32m = detect_f32(emb);
  int tid = threadIdx.x, wid = tid >> 6, lane = tid & 63;
  int l15 = lane & 15, lq = lane >> 4;
  int blk = blockIdx.x;
  if (blk < 256) {                          // xs2[s][wid][ch][lane][8]
    int s = blk, b = wid * 16 + l15;
    size_t roff = (size_t)idx[b * 256 + s] * 300;
    u16* dst = xs2 + ((size_t)(s * 4 + wid) * 10) * 512 + lane * 8;
    #pragma unroll
    for (int ch = 0; ch < 10; ch++) {
      short8 v;
      #pragma unroll
      for (int j = 0; j < 8; j++) {
        int k = ch * 32 + lq * 8 + j;
        v[j] = (k < 300) ? (short)f2b(rdf(emb, roff + k, f32m)) : (short)0;
      }
      *(short8*)(dst + ch * 512) = v;
    }
  } else if (blk < 304) {                   // wp2[w=dir*96+slice*3+g][ch][lane][8]
    int w = (blk - 256) * 4 + wid;          // 0..191
    int dir = w / 96, rem = w - dir * 96;
    int slice = rem / 3, g = rem - slice * 3;
    const void* wp = dir ? wih_b : wih_f;
    size_t roff = (size_t)(g * 512 + slice * 16 + l15) * 300;
    u16* dst = wp2 + ((size_t)w * 10) * 512 + lane * 8;
    #pragma unroll
    for (int ch = 0; ch < 10; ch++) {
      short8 v;
      #pragma unroll
      for (int j = 0; j < 8; j++) {
        int k = ch * 32 + lq * 8 + j;
        v[j] = (k < 300) ? (short)f2b(rdf(wp, roff + k, f32m)) : (short)0;
      }
      *(short8*)(dst + ch * 512) = v;
    }
  } else if (blk < 1072) {                  // whh_n[dir*1536+rr][c]
    int row = (blk - 304) * 4 + wid;        // 0..3071
    int dir = (row >= 1536);
    int rr = row - dir * 1536;
    const void* p = dir ? whh_b : whh_f;
    u16* dst = whh_n + (size_t)row * 512;
    for (int c = lane; c < 512; c += 64)
      dst[c] = f2b(rdf(p, (size_t)rr * 512 + c, f32m));
  } else if (blk < 1078) {                  // linw_n[row][c], 21 rows x 1024
    int row = (blk - 1072) * 4 + wid;
    if (row < NC)
      for (int c = lane; c < 1024; c += 64)
        linw_n[(size_t)row * 1024 + c] = f2b(rdf(linW, (size_t)row * 1024 + c, f32m));
  } else {                                  // fused biases + linb (f32)
    for (int i = tid; i < 4096; i += 256) {
      int dir = i >> 11, vec = (i >> 9) & 3, u = i & 511;
      const void* bi = dir ? bih_b : bih_f;
      const void* bh = dir ? bhh_b : bhh_f;
      float v;
      if (vec == 0)      v = rdf(bi, u, f32m) + rdf(bh, u, f32m);
      else if (vec == 1) v = rdf(bi, 512 + u, f32m) + rdf(bh, 512 + u, f32m);
      else if (vec == 2) v = rdf(bi, 1024 + u, f32m);
      else               v = rdf(bh, 1024 + u, f32m);
      bias_n[i] = v;
    }
    for (int i = tid; i < NC; i += 256) linb_n[i] = rdf(linb, i, f32m);
  }
}

// ---------------- persistent bidirectional GRU scan -----------------------------------
// R8: SELF-VALIDATING TAGGED h EXCHANGE — zero flags, zero fences, zero barriers.
// Every 8B word of the h exchange carries a 16-bit step tag next to 3 bf16 payloads.
// An aligned 8B store is a single coherent-point transaction (it is exactly the
// encoding atomic stores lower to), so tag+payload cannot tear. Writers fire-and-
// forget sc0sc1 stores (no vmcnt drain, no flag publish); readers poll the DATA
// until all tags == t — poll and payload load are the same round trip. This cuts
// the per-step serial chain from 4 coherent round trips (store-ack, flag-visible,
// poll-detect, h-load) to ~1.5 (store-visible overlapped with reader's phase 1,
// then one successful load).
// Safety: reader seeing tag t on every (g,b) quantum proves every wave of every
// block finished its step t-1 reads (each wave's stores are data-dependent on its
// loads), so overwriting the parity buffer (tags t-1 -> t+1) is race-free. Tags
// are monotonic per parity (t, t+2, ...), so stale data never false-validates.
// The launch-time memset resets tags each run.
__global__ __launch_bounds__(256) void scan_kernel(
    const u16* __restrict__ whh_n, const float* __restrict__ bias_n,
    const u16* __restrict__ xs2, const u16* __restrict__ wp2,
    char* __restrict__ hbuf2, u16* __restrict__ hs) {
  __shared__ u16 Wl[48][520];               // 49,920 B
  int wg = blockIdx.x;
  int dir = wg >> 5, slice = wg & 31, j0 = slice * 16;
  int tid = threadIdx.x, wid = tid >> 6, lane = tid & 63;
  int l15 = lane & 15, lq = lane >> 4;

  for (int q = tid; q < 48 * 256; q += 256) {
    int lr = q >> 8, qq = q & 255;
    int grp = lr >> 4, uu = lr & 15;
    const u32* srow = (const u32*)(whh_n + (size_t)(dir * 1536 + grp * 512 + j0 + uu) * 512);
    *(u32*)((char*)&Wl[lr][0] + qq * 4) = srow[qq];
  }
  const float* bb = bias_n + dir * 2048;
  float brz0[4], brz1[4], bin_[4], bhn_[4];
  #pragma unroll
  for (int r = 0; r < 4; r++) {
    int u = j0 + lq * 4 + r;
    brz0[r] = bb[u];
    brz1[r] = bb[512 + u];
    bin_[r] = bb[1024 + u];
    bhn_[r] = bb[1536 + u];
  }
  float hown[4] = {0.f, 0.f, 0.f, 0.f};     // private fp32 state: (b, j0+lq*4+r)
  int b = wid * 16 + l15;                   // this lane's batch row
  const u16* wbase = wp2 + ((size_t)(dir * 96 + slice * 3) * 10) * 512 + lane * 8;
  const size_t hs_dir = (size_t)dir * SB * HH;
  const int g_mine = 2 * slice + (lq >> 1); // the 8-elem group this lane-pair produces
  __syncthreads();                          // Wl ready; no barriers after this point

  for (int t = 0; t < 256; t++) {
    int s = dir ? (255 - t) : t;
    // ---- phase 1: input-gate MFMAs (no h dependency; overlaps producers' stores) ----
    const u16* xbase = xs2 + ((size_t)(s * 4 + wid) * 10) * 512 + lane * 8;
    float4_ accr = (float4_)(0.f), accz = (float4_)(0.f);
    float4_ accni = (float4_)(0.f), accnh = (float4_)(0.f);
    short8 xf[10];
    #pragma unroll
    for (int ch = 0; ch < 10; ch++) xf[ch] = *(const short8*)(xbase + ch * 512);
    #pragma unroll
    for (int ch = 0; ch < 10; ch++) {
      short8 a0 = *(const short8*)(wbase + (size_t)ch * 512);
      short8 a1 = *(const short8*)(wbase + (size_t)(10 + ch) * 512);
      short8 a2 = *(const short8*)(wbase + (size_t)(20 + ch) * 512);
      accr  = __builtin_amdgcn_mfma_f32_16x16x32_bf16(a0, xf[ch], accr, 0, 0, 0);
      accz  = __builtin_amdgcn_mfma_f32_16x16x32_bf16(a1, xf[ch], accz, 0, 0, 0);
      accni = __builtin_amdgcn_mfma_f32_16x16x32_bf16(a2, xf[ch], accni, 0, 0, 0);
    }
    // ---- phase 2+3 fused: self-validating h read (poll == payload load) ----
    const char* hr = hbuf2 + ((size_t)(dir * 2 + (t & 1)) << 17);
    const char* hrow = hr + ((size_t)b << 11);
    u32 tg = (u32)t;
    short8 hf[16];
    u32 need = 0xffffu;
    uint4_ r4[16];
    uint2_ r2[16];
    long tries = 0;
    while (true) {
      #pragma unroll
      for (int k = 0; k < 16; k++) if ((need >> k) & 1u) {
        const char* p = hrow + (((u32)(k * 4) + (u32)lq) << 5);
        asm volatile("global_load_dwordx4 %0, %1, off sc0 sc1"
                     : "=v"(r4[k]) : "v"(p));
        asm volatile("global_load_dwordx2 %0, %1, off offset:16 sc0 sc1"
                     : "=v"(r2[k]) : "v"(p));
      }
      asm volatile("s_waitcnt vmcnt(0)" ::: "memory");
      __builtin_amdgcn_sched_barrier(0);    // keep tag checks below the waitcnt
      #pragma unroll
      for (int k = 0; k < 16; k++) if ((need >> k) & 1u) {
        u32 a0 = r4[k].x, a1 = r4[k].y, a2 = r4[k].z, a3 = r4[k].w;
        u32 c0 = r2[k].x, c1 = r2[k].y;
        bool ok = ((a1 >> 16) == tg) & ((a3 >> 16) == tg) & ((c1 >> 16) == tg);
        if (ok) {
          union { u32 w[4]; short8 s; } u;
          u.w[0] = a0;
          u.w[1] = (a1 & 0xffffu) | (a2 << 16);
          u.w[2] = (a2 >> 16) | (a3 << 16);
          u.w[3] = c0;
          hf[k] = u.s;
          need &= ~(1u << k);
        }
      }
      if (__ballot(need) == 0ull) break;
      if (++tries > (1L << 20)) break;      // deadlock -> finite tripwire
    }
    // ---- h MFMAs ----
    #pragma unroll
    for (int k = 0; k < 16; k++) {
      int kc = k * 32 + lq * 8;
      short8 a0 = *(const short8*)&Wl[l15][kc];
      short8 a1 = *(const short8*)&Wl[16 + l15][kc];
      short8 a2 = *(const short8*)&Wl[32 + l15][kc];
      accr  = __builtin_amdgcn_mfma_f32_16x16x32_bf16(a0, hf[k], accr, 0, 0, 0);
      accz  = __builtin_amdgcn_mfma_f32_16x16x32_bf16(a1, hf[k], accz, 0, 0, 0);
      accnh = __builtin_amdgcn_mfma_f32_16x16x32_bf16(a2, hf[k], accnh, 0, 0, 0);
    }
    // ---- phase 4: gates (f32), state update, tagged publish (fire-and-forget) ----
    union { ushort4_ v; u64 q; } ho;
    #pragma unroll
    for (int r = 0; r < 4; r++) {
      float rr = sigm(accr[r] + brz0[r]);
      float zz = sigm(accz[r] + brz1[r]);
      float nn = tanh_f(accni[r] + bin_[r] + rr * (accnh[r] + bhn_[r]));
      float hn = (1.f - zz) * nn + zz * hown[r];
      hown[r] = hn;
      ho.v[r] = f2b(hn);
    }
    {
      u32 tgs = (u32)(t + 1);
      u64 o64 = ho.q;
      u64 p64 = (u64)__shfl_xor((long long)o64, 16);   // partner lane's 4 bf16
      char* hw = hbuf2 + ((size_t)(dir * 2 + ((t + 1) & 1)) << 17);
      char* dst = hw + ((size_t)b << 11) + ((u32)g_mine << 5);
      if ((lq & 1) == 0) {
        uint4_ w;
        w.x = (u32)o64;                                       // e0,e1
        w.y = (u32)((o64 >> 32) & 0xffffu) | (tgs << 16);     // e2,tag
        w.z = (u32)(o64 >> 48) | ((u32)(p64 & 0xffffu) << 16);// e3,e4
        w.w = (u32)((p64 >> 16) & 0xffffu) | (tgs << 16);     // e5,tag
        asm volatile("global_store_dwordx4 %0, %1, off sc0 sc1"
                     :: "v"(dst), "v"(w) : "memory");
      } else {
        uint2_ w;
        w.x = (u32)(o64 >> 32);                               // e6,e7
        w.y = (tgs << 16);                                    // pad,tag
        asm volatile("global_store_dwordx2 %0, %1, off offset:16 sc0 sc1"
                     :: "v"(dst), "v"(w) : "memory");
      }
    }
    // hs trace store: normal cached store; kernel-end flush makes it visible to
    // final_kernel (separate dispatch, stream-ordered).
    *(ushort4_*)(hs + hs_dir + (size_t)(s * 64 + b) * HH + j0 + lq * 4) = ho.v;
  }
}

// ---------------- final: logits -> log_softmax -> out[B][21][S] (f32) (unchanged) -----
__global__ __launch_bounds__(256) void final_kernel(
    const u16* __restrict__ hs, const u16* __restrict__ linw_n,
    const float* __restrict__ linb_n, float* __restrict__ out) {
  __shared__ u16 Wl[NC][1032];
  __shared__ float lp[64][NC];
  __shared__ float lbs[NC];
  int tid = threadIdx.x, wid = tid >> 6, lane = tid & 63;
  int b = blockIdx.x, s0 = blockIdx.y * 64;
  for (int q = tid; q < NC * 512; q += 256) {
    int c = q >> 9, qq = q & 511;
    *(u32*)((char*)&Wl[c][0] + qq * 4) = ((const u32*)linw_n)[c * 512 + qq];
  }
  if (tid < NC) lbs[tid] = linb_n[tid];
  __syncthreads();
  #pragma unroll 1
  for (int i = 0; i < 16; i++) {
    int p = wid * 16 + i;
    int s = s0 + p;
    const u16* hfp = hs + (size_t)(s * 64 + b) * HH + lane * 8;
    const u16* hbp = hfp + (size_t)SB * HH;
    short8 va = *(const short8*)hfp;
    short8 vb = *(const short8*)hbp;
    float fa[8], fb[8];
    #pragma unroll
    for (int e = 0; e < 8; e++) { fa[e] = b2f((u16)va[e]); fb[e] = b2f((u16)vb[e]); }
    float mine = 0.f, mx = -1e30f;
    float lg[NC];
    #pragma unroll
    for (int c = 0; c < NC; c++) {
      short8 w1 = *(const short8*)((char*)&Wl[c][0] + lane * 16);
      short8 w2 = *(const short8*)((char*)&Wl[c][0] + 1024 + lane * 16);
      float ps = 0.f;
      #pragma unroll
      for (int e = 0; e < 8; e++)
        ps += fa[e] * b2f((u16)w1[e]) + fb[e] * b2f((u16)w2[e]);
      #pragma unroll
      for (int off = 32; off; off >>= 1) ps += __shfl_xor(ps, off);
      lg[c] = ps + lbs[c];
      mx = fmaxf(mx, lg[c]);
      if (lane == c) mine = lg[c];
    }
    float se = 0.f;
    #pragma unroll
    for (int c = 0; c < NC; c++) se += __expf(lg[c] - mx);
    float lse = mx + __logf(se);
    if (lane < NC) lp[p][lane] = mine - lse;
  }
  __syncthreads();
  for (int e = tid; e < NC * 64; e += 256) {
    int c = e >> 6, q = e & 63;
    out[((size_t)b * NC + c) * 256 + s0 + q] = lp[q][c];
  }
}

extern "C" void kernel_launch(void* const* d_in, const int* in_sizes, int n_in,
                              void* d_out, int out_size, void* d_ws, size_t ws_size,
                              hipStream_t stream) {
  (void)in_sizes; (void)n_in;
  const int* idx = (const int*)d_in[0];
  const void *emb = d_in[1], *wih_f = d_in[2], *whh_f = d_in[3];
  const void *bih_f = d_in[4], *bhh_f = d_in[5], *wih_b = d_in[6];
  const void *whh_b = d_in[7], *bih_b = d_in[8], *bhh_b = d_in[9];
  const void *linW = d_in[10], *linb = d_in[11];

  if (ws_size < (size_t)WS_NEED) {
    float v = -100.0f - (float)(unsigned)(ws_size >> 20);
    fallback_kernel<<<(out_size + 255) / 256, 256, 0, stream>>>((float*)d_out, out_size, v);
    return;
  }
  char* ws = (char*)d_ws;
  char*  hbuf2  = ws + OFF_HBUF;
  float* bias_n = (float*)(ws + OFF_BIAS);
  float* linb_n = (float*)(ws + OFF_LINB);
  u16*   linw_n = (u16*)(ws + OFF_LINW);
  u16*   whh_n  = (u16*)(ws + OFF_WHH);
  u16*   xs2    = (u16*)(ws + OFF_XS);
  u16*   wp2    = (u16*)(ws + OFF_WP);
  u16*   hs     = (u16*)(ws + OFF_HS);

  hipMemsetAsync(ws, 0, OFF_BIAS, stream);  // reset all exchange tags (re-run safe)
  prep_kernel<<<1079, 256, 0, stream>>>(idx, emb, wih_f, wih_b, whh_f, whh_b,
                                        bih_f, bih_b, bhh_f, bhh_b, linW, linb,
                                        xs2, wp2, whh_n, linw_n, bias_n, linb_n);
  scan_kernel<<<64, 256, 0, stream>>>(whh_n, bias_n, xs2, wp2, hbuf2, hs);
  final_kernel<<<dim3(64, 4), 256, 0, stream>>>(hs, linw_n, linb_n, (float*)d_out);
}

// Round 3
// 2048.716 us; speedup vs baseline: 1.0510x; 1.0510x over previous
//
#include <hip/hip_runtime.h>

typedef unsigned short u16;
typedef unsigned int u32;
typedef unsigned long long u64;
typedef __attribute__((ext_vector_type(8))) short short8;    // 8 bf16 = 4 VGPRs (MFMA A/B frag)
typedef __attribute__((ext_vector_type(4))) float float4_;   // MFMA C/D frag
typedef __attribute__((ext_vector_type(4))) u16 ushort4_;    // 8B vector of bf16
typedef __attribute__((ext_vector_type(4))) u32 uint4_;
typedef __attribute__((ext_vector_type(2))) u32 uint2_;

#define SB 16384   // S*B
#define HH 512     // H
#define NC 21      // C+1

// ws layout (bytes). All offsets 16B-aligned.
// hbuf2: tagged h exchange: [dir][parity][b=64][g=64][32B rec]  (2*2*64*2048 = 524288)
//   record g (owns h[g*8..g*8+7]): bytes 0-15: [e0,e1,e2,tag][e3,e4,e5,tag]
//                                  bytes 16-23: [e6,e7,pad,tag], bytes 24-31 pad.
#define OFF_VOTE 0u          // xcd vote: [dir]{mask,cnt} u32x4      (4096, mostly pad)
#define OFF_HBUF 4096u       // tagged h dbuf                        (524288) -> 528384
#define OFF_BIAS 528384u     // bias_n: [dir][4][512] f32            (16384)  -> 544768
#define OFF_LINB 544768u     // linb_n: 21 f32 (+pad)                (256)    -> 545024
#define OFF_LINW 545024u     // linw_n: [21][1024] bf16              (43008)  -> 588032
#define OFF_WHH  588032u     // whh_n: [dir*1536+row][512] bf16      (3145728)-> 3733760
#define OFF_XS   3733760u    // xs2 frag-packed: [s][4][10][512] bf16(10485760)->14219520
#define OFF_WP   14219520u   // wp2 frag-packed: [192][10][512] bf16 (1966080)->16185600
#define OFF_HS   16185600u   // hs: [dir][SB][512] bf16              (33554432)->49740032
#define WS_NEED  49740032u

__device__ __forceinline__ float b2f(u16 u) {
  union { u32 i; float f; } x; x.i = ((u32)u) << 16; return x.f;
}
__device__ __forceinline__ u16 f2b(float f) {  // RNE f32->bf16
  union { float f; u32 i; } x; x.f = f;
  u32 r = x.i + 0x7fffu + ((x.i >> 16) & 1u);
  return (u16)(r >> 16);
}
__device__ __forceinline__ float sigm(float x) { return 1.f / (1.f + __expf(-x)); }
__device__ __forceinline__ float tanh_f(float x) {
  x = fminf(fmaxf(x, -15.f), 15.f);
  float e = __expf(2.f * x);
  return (e - 1.f) / (e + 1.f);
}

// Runtime storage-dtype probe (kept from R6; cheap, in-bounds either way).
__device__ __forceinline__ bool detect_f32(const void* emb) {
  u16 v = ((const u16*)emb)[threadIdx.x & 63];
  int e = (v >> 7) & 0xff;
  return __ballot(e >= 147) != 0ull;
}
__device__ __forceinline__ float rdf(const void* p, size_t i, bool f32m) {
  return f32m ? ((const float*)p)[i] : b2f(((const u16*)p)[i]);
}

__global__ __launch_bounds__(256) void fallback_kernel(float* out, int n, float v) {
  int i = blockIdx.x * 256 + threadIdx.x;
  if (i < n) out[i] = v;
}

// ---------------- normalize everything into canonical ws buffers (unchanged) ----------
__global__ __launch_bounds__(256) void prep_kernel(
    const int* __restrict__ idx, const void* __restrict__ emb,
    const void* __restrict__ wih_f, const void* __restrict__ wih_b,
    const void* __restrict__ whh_f, const void* __restrict__ whh_b,
    const void* __restrict__ bih_f, const void* __restrict__ bih_b,
    const void* __restrict__ bhh_f, const void* __restrict__ bhh_b,
    const void* __restrict__ linW, const void* __restrict__ linb,
    u16* __restrict__ xs2, u16* __restrict__ wp2, u16* __restrict__ whh_n,
    u16* __restrict__ linw_n, float* __restrict__ bias_n, float* __restrict__ linb_n) {
  bool f32m = detect_f32(emb);
  int tid = threadIdx.x, wid = tid >> 6, lane = tid & 63;
  int l15 = lane & 15, lq = lane >> 4;
  int blk = blockIdx.x;
  if (blk < 256) {                          // xs2[s][wid][ch][lane][8]
    int s = blk, b = wid * 16 + l15;
    size_t roff = (size_t)idx[b * 256 + s] * 300;
    u16* dst = xs2 + ((size_t)(s * 4 + wid) * 10) * 512 + lane * 8;
    #pragma unroll
    for (int ch = 0; ch < 10; ch++) {
      short8 v;
      #pragma unroll
      for (int j = 0; j < 8; j++) {
        int k = ch * 32 + lq * 8 + j;
        v[j] = (k < 300) ? (short)f2b(rdf(emb, roff + k, f32m)) : (short)0;
      }
      *(short8*)(dst + ch * 512) = v;
    }
  } else if (blk < 304) {                   // wp2[w=dir*96+slice*3+g][ch][lane][8]
    int w = (blk - 256) * 4 + wid;          // 0..191
    int dir = w / 96, rem = w - dir * 96;
    int slice = rem / 3, g = rem - slice * 3;
    const void* wp = dir ? wih_b : wih_f;
    size_t roff = (size_t)(g * 512 + slice * 16 + l15) * 300;
    u16* dst = wp2 + ((size_t)w * 10) * 512 + lane * 8;
    #pragma unroll
    for (int ch = 0; ch < 10; ch++) {
      short8 v;
      #pragma unroll
      for (int j = 0; j < 8; j++) {
        int k = ch * 32 + lq * 8 + j;
        v[j] = (k < 300) ? (short)f2b(rdf(wp, roff + k, f32m)) : (short)0;
      }
      *(short8*)(dst + ch * 512) = v;
    }
  } else if (blk < 1072) {                  // whh_n[dir*1536+rr][c]
    int row = (blk - 304) * 4 + wid;        // 0..3071
    int dir = (row >= 1536);
    int rr = row - dir * 1536;
    const void* p = dir ? whh_b : whh_f;
    u16* dst = whh_n + (size_t)row * 512;
    for (int c = lane; c < 512; c += 64)
      dst[c] = f2b(rdf(p, (size_t)rr * 512 + c, f32m));
  } else if (blk < 1078) {                  // linw_n[row][c], 21 rows x 1024
    int row = (blk - 1072) * 4 + wid;
    if (row < NC)
      for (int c = lane; c < 1024; c += 64)
        linw_n[(size_t)row * 1024 + c] = f2b(rdf(linW, (size_t)row * 1024 + c, f32m));
  } else {                                  // fused biases + linb (f32)
    for (int i = tid; i < 4096; i += 256) {
      int dir = i >> 11, vec = (i >> 9) & 3, u = i & 511;
      const void* bi = dir ? bih_b : bih_f;
      const void* bh = dir ? bhh_b : bhh_f;
      float v;
      if (vec == 0)      v = rdf(bi, u, f32m) + rdf(bh, u, f32m);
      else if (vec == 1) v = rdf(bi, 512 + u, f32m) + rdf(bh, 512 + u, f32m);
      else if (vec == 2) v = rdf(bi, 1024 + u, f32m);
      else               v = rdf(bh, 1024 + u, f32m);
      bias_n[i] = v;
    }
    for (int i = tid; i < NC; i += 256) linb_n[i] = rdf(linb, i, f32m);
  }
}

// Tagged h read: poll the data itself until all 16 records carry tag tg.
// FULLSC=true  -> sc0 sc1 loads (coherent point / MALL; mapping-independent, R2 path)
// FULLSC=false -> sc0 loads (L1-bypass, served by this XCD's shared L2; requires all
//                 producers of this direction on the same XCD — guaranteed by the vote)
template<bool FULLSC>
__device__ __forceinline__ void poll_read(const char* hrow, int lq, u32 tg, short8* hf) {
  u32 need = 0xffffu;
  uint4_ r4[16];
  uint2_ r2[16];
  long tries = 0;
  while (true) {
    #pragma unroll
    for (int k = 0; k < 16; k++) if ((need >> k) & 1u) {
      const char* p = hrow + (((u32)(k * 4) + (u32)lq) << 5);
      if (FULLSC) {
        asm volatile("global_load_dwordx4 %0, %1, off sc0 sc1" : "=v"(r4[k]) : "v"(p));
        asm volatile("global_load_dwordx2 %0, %1, off offset:16 sc0 sc1" : "=v"(r2[k]) : "v"(p));
      } else {
        asm volatile("global_load_dwordx4 %0, %1, off sc0" : "=v"(r4[k]) : "v"(p));
        asm volatile("global_load_dwordx2 %0, %1, off offset:16 sc0" : "=v"(r2[k]) : "v"(p));
      }
    }
    asm volatile("s_waitcnt vmcnt(0)" ::: "memory");
    __builtin_amdgcn_sched_barrier(0);    // keep tag checks below the waitcnt
    #pragma unroll
    for (int k = 0; k < 16; k++) if ((need >> k) & 1u) {
      u32 a0 = r4[k].x, a1 = r4[k].y, a2 = r4[k].z, a3 = r4[k].w;
      u32 c0 = r2[k].x, c1 = r2[k].y;
      bool ok = ((a1 >> 16) == tg) & ((a3 >> 16) == tg) & ((c1 >> 16) == tg);
      if (ok) {
        union { u32 w[4]; short8 s; } u;
        u.w[0] = a0;
        u.w[1] = (a1 & 0xffffu) | (a2 << 16);
        u.w[2] = (a2 >> 16) | (a3 << 16);
        u.w[3] = c0;
        hf[k] = u.s;
        need &= ~(1u << k);
      }
    }
    if (__ballot(need) == 0ull) break;
    if (++tries > (1L << 20)) break;      // deadlock -> finite tripwire
    if (tries > 2) __builtin_amdgcn_s_sleep(1);
  }
}

// ---------------- persistent bidirectional GRU scan -----------------------------------
// R9: INTRA-XCD L2 h EXCHANGE. Blocks round-robin XCDs by blockIdx%8 [m09], so with
// grid=256 the workers at blk%8==0 (dir 0) / blk%8==1 (dir 1) each occupy all 32 CUs
// of one XCD. Within one XCD the shared L2 IS a coherent point: sc0 stores write it,
// sc0 loads (L1-bypass) read it — ~200-cycle round trips and L2-bandwidth all-to-all,
// instead of the ~1 us MALL fabric round trips that dominated R7/R8.
// Correctness does NOT depend on the mapping heuristic:
//   (1) every 8B word of the exchange carries a 16-bit step tag (tearing-free, since
//       an aligned 8B store is a single transaction); readers poll the data itself.
//   (2) a one-time startup vote (HW_REG_XCC_ID, agent-scope atomics) verifies that
//       each direction's 32 blocks share one XCD; if not, that direction uses the
//       proven R8 sc0sc1 (MALL) path. Vote ordering: the mask-OR's ack is drained
//       (vmcnt) before the count increment, so cnt==32 implies all masks landed.
// Overwrite-safety (unchanged induction): a block may write tags t+1 into parity P
// only after its step-t reads succeeded, which requires tag-t records from every
// lane-pair of every block — each of which is data-dependent on that wave's step
// t-1 reads of P. Tags are monotonic per parity; launch-time memset resets them.
__global__ __launch_bounds__(256) void scan_kernel(
    const u16* __restrict__ whh_n, const float* __restrict__ bias_n,
    const u16* __restrict__ xs2, const u16* __restrict__ wp2,
    char* __restrict__ hbuf2, u16* __restrict__ hs, u32* __restrict__ vote) {
  __shared__ u16 Wl[48][520];               // 49,920 B
  __shared__ u32 fast_sh;
  int wg = blockIdx.x;
  int xsel = wg & 7;
  if (xsel >= 2) return;                    // 192 idle blocks exit immediately
  int dir = xsel, slice = wg >> 3, j0 = slice * 16;
  int tid = threadIdx.x, wid = tid >> 6, lane = tid & 63;
  int l15 = lane & 15, lq = lane >> 4;

  // ---- startup vote: are all 32 blocks of this direction on one XCD? ----
  if (tid == 0) {
    u32 xcc = __builtin_amdgcn_s_getreg(63508);   // HW_REG_XCC_ID(20), off 0, sz 32
    u32* vm = vote + dir * 2;                     // {mask, cnt}
    __hip_atomic_fetch_or(&vm[0], 1u << (xcc & 31), __ATOMIC_RELAXED,
                          __HIP_MEMORY_SCOPE_AGENT);
    __asm__ volatile("s_waitcnt vmcnt(0)" ::: "memory");  // OR ack before cnt++
    __hip_atomic_fetch_add(&vm[1], 1u, __ATOMIC_RELAXED, __HIP_MEMORY_SCOPE_AGENT);
    for (long it = 0; it < (1L << 20); ++it) {
      u32 c = __hip_atomic_load(&vm[1], __ATOMIC_RELAXED, __HIP_MEMORY_SCOPE_AGENT);
      if (c >= 32) break;
      __builtin_amdgcn_s_sleep(2);
    }
    u32 m = __hip_atomic_load(&vm[0], __ATOMIC_RELAXED, __HIP_MEMORY_SCOPE_AGENT);
    fast_sh = (__popc(m) == 1) ? 1u : 0u;
  }

  for (int q = tid; q < 48 * 256; q += 256) {
    int lr = q >> 8, qq = q & 255;
    int grp = lr >> 4, uu = lr & 15;
    const u32* srow = (const u32*)(whh_n + (size_t)(dir * 1536 + grp * 512 + j0 + uu) * 512);
    *(u32*)((char*)&Wl[lr][0] + qq * 4) = srow[qq];
  }
  const float* bb = bias_n + dir * 2048;
  float brz0[4], brz1[4], bin_[4], bhn_[4];
  #pragma unroll
  for (int r = 0; r < 4; r++) {
    int u = j0 + lq * 4 + r;
    brz0[r] = bb[u];
    brz1[r] = bb[512 + u];
    bin_[r] = bb[1024 + u];
    bhn_[r] = bb[1536 + u];
  }
  float hown[4] = {0.f, 0.f, 0.f, 0.f};     // private fp32 state: (b, j0+lq*4+r)
  int b = wid * 16 + l15;                   // this lane's batch row
  const u16* wbase = wp2 + ((size_t)(dir * 96 + slice * 3) * 10) * 512 + lane * 8;
  const size_t hs_dir = (size_t)dir * SB * HH;
  const int g_mine = 2 * slice + (lq >> 1); // the 8-elem group this lane-pair produces
  __syncthreads();                          // Wl + fast_sh ready; no barriers after
  const bool fast = fast_sh != 0u;

  for (int t = 0; t < 256; t++) {
    int s = dir ? (255 - t) : t;
    // ---- phase 1: input-gate MFMAs (no h dependency; overlaps producers' stores) ----
    const u16* xbase = xs2 + ((size_t)(s * 4 + wid) * 10) * 512 + lane * 8;
    float4_ accr = (float4_)(0.f), accz = (float4_)(0.f);
    float4_ accni = (float4_)(0.f), accnh = (float4_)(0.f);
    short8 xf[10];
    #pragma unroll
    for (int ch = 0; ch < 10; ch++) xf[ch] = *(const short8*)(xbase + ch * 512);
    #pragma unroll
    for (int ch = 0; ch < 10; ch++) {
      short8 a0 = *(const short8*)(wbase + (size_t)ch * 512);
      short8 a1 = *(const short8*)(wbase + (size_t)(10 + ch) * 512);
      short8 a2 = *(const short8*)(wbase + (size_t)(20 + ch) * 512);
      accr  = __builtin_amdgcn_mfma_f32_16x16x32_bf16(a0, xf[ch], accr, 0, 0, 0);
      accz  = __builtin_amdgcn_mfma_f32_16x16x32_bf16(a1, xf[ch], accz, 0, 0, 0);
      accni = __builtin_amdgcn_mfma_f32_16x16x32_bf16(a2, xf[ch], accni, 0, 0, 0);
    }
    // ---- phase 2+3 fused: self-validating h read (poll == payload load) ----
    const char* hrow = hbuf2 + ((size_t)(dir * 2 + (t & 1)) << 17) + ((size_t)b << 11);
    short8 hf[16];
    if (fast) poll_read<false>(hrow, lq, (u32)t, hf);
    else      poll_read<true >(hrow, lq, (u32)t, hf);
    // ---- h MFMAs ----
    #pragma unroll
    for (int k = 0; k < 16; k++) {
      int kc = k * 32 + lq * 8;
      short8 a0 = *(const short8*)&Wl[l15][kc];
      short8 a1 = *(const short8*)&Wl[16 + l15][kc];
      short8 a2 = *(const short8*)&Wl[32 + l15][kc];
      accr  = __builtin_amdgcn_mfma_f32_16x16x32_bf16(a0, hf[k], accr, 0, 0, 0);
      accz  = __builtin_amdgcn_mfma_f32_16x16x32_bf16(a1, hf[k], accz, 0, 0, 0);
      accnh = __builtin_amdgcn_mfma_f32_16x16x32_bf16(a2, hf[k], accnh, 0, 0, 0);
    }
    // ---- phase 4: gates (f32), state update, tagged publish (fire-and-forget) ----
    union { ushort4_ v; u64 q; } ho;
    #pragma unroll
    for (int r = 0; r < 4; r++) {
      float rr = sigm(accr[r] + brz0[r]);
      float zz = sigm(accz[r] + brz1[r]);
      float nn = tanh_f(accni[r] + bin_[r] + rr * (accnh[r] + bhn_[r]));
      float hn = (1.f - zz) * nn + zz * hown[r];
      hown[r] = hn;
      ho.v[r] = f2b(hn);
    }
    {
      u32 tgs = (u32)(t + 1);
      u64 o64 = ho.q;
      u64 p64 = (u64)__shfl_xor((long long)o64, 16);   // partner lane's 4 bf16
      char* hw = hbuf2 + ((size_t)(dir * 2 + ((t + 1) & 1)) << 17);
      char* dst = hw + ((size_t)b << 11) + ((u32)g_mine << 5);
      if ((lq & 1) == 0) {
        uint4_ w;
        w.x = (u32)o64;                                       // e0,e1
        w.y = (u32)((o64 >> 32) & 0xffffu) | (tgs << 16);     // e2,tag
        w.z = (u32)(o64 >> 48) | ((u32)(p64 & 0xffffu) << 16);// e3,e4
        w.w = (u32)((p64 >> 16) & 0xffffu) | (tgs << 16);     // e5,tag
        if (fast)
          asm volatile("global_store_dwordx4 %0, %1, off sc0"
                       :: "v"(dst), "v"(w) : "memory");
        else
          asm volatile("global_store_dwordx4 %0, %1, off sc0 sc1"
                       :: "v"(dst), "v"(w) : "memory");
      } else {
        uint2_ w;
        w.x = (u32)(o64 >> 32);                               // e6,e7
        w.y = (tgs << 16);                                    // pad,tag
        if (fast)
          asm volatile("global_store_dwordx2 %0, %1, off offset:16 sc0"
                       :: "v"(dst), "v"(w) : "memory");
        else
          asm volatile("global_store_dwordx2 %0, %1, off offset:16 sc0 sc1"
                       :: "v"(dst), "v"(w) : "memory");
      }
    }
    // hs trace store: normal cached store; kernel-end flush makes it visible to
    // final_kernel (separate dispatch, stream-ordered).
    *(ushort4_*)(hs + hs_dir + (size_t)(s * 64 + b) * HH + j0 + lq * 4) = ho.v;
  }
}

// ---------------- final: logits -> log_softmax -> out[B][21][S] (f32) (unchanged) -----
__global__ __launch_bounds__(256) void final_kernel(
    const u16* __restrict__ hs, const u16* __restrict__ linw_n,
    const float* __restrict__ linb_n, float* __restrict__ out) {
  __shared__ u16 Wl[NC][1032];
  __shared__ float lp[64][NC];
  __shared__ float lbs[NC];
  int tid = threadIdx.x, wid = tid >> 6, lane = tid & 63;
  int b = blockIdx.x, s0 = blockIdx.y * 64;
  for (int q = tid; q < NC * 512; q += 256) {
    int c = q >> 9, qq = q & 511;
    *(u32*)((char*)&Wl[c][0] + qq * 4) = ((const u32*)linw_n)[c * 512 + qq];
  }
  if (tid < NC) lbs[tid] = linb_n[tid];
  __syncthreads();
  #pragma unroll 1
  for (int i = 0; i < 16; i++) {
    int p = wid * 16 + i;
    int s = s0 + p;
    const u16* hfp = hs + (size_t)(s * 64 + b) * HH + lane * 8;
    const u16* hbp = hfp + (size_t)SB * HH;
    short8 va = *(const short8*)hfp;
    short8 vb = *(const short8*)hbp;
    float fa[8], fb[8];
    #pragma unroll
    for (int e = 0; e < 8; e++) { fa[e] = b2f((u16)va[e]); fb[e] = b2f((u16)vb[e]); }
    float mine = 0.f, mx = -1e30f;
    float lg[NC];
    #pragma unroll
    for (int c = 0; c < NC; c++) {
      short8 w1 = *(const short8*)((char*)&Wl[c][0] + lane * 16);
      short8 w2 = *(const short8*)((char*)&Wl[c][0] + 1024 + lane * 16);
      float ps = 0.f;
      #pragma unroll
      for (int e = 0; e < 8; e++)
        ps += fa[e] * b2f((u16)w1[e]) + fb[e] * b2f((u16)w2[e]);
      #pragma unroll
      for (int off = 32; off; off >>= 1) ps += __shfl_xor(ps, off);
      lg[c] = ps + lbs[c];
      mx = fmaxf(mx, lg[c]);
      if (lane == c) mine = lg[c];
    }
    float se = 0.f;
    #pragma unroll
    for (int c = 0; c < NC; c++) se += __expf(lg[c] - mx);
    float lse = mx + __logf(se);
    if (lane < NC) lp[p][lane] = mine - lse;
  }
  __syncthreads();
  for (int e = tid; e < NC * 64; e += 256) {
    int c = e >> 6, q = e & 63;
    out[((size_t)b * NC + c) * 256 + s0 + q] = lp[q][c];
  }
}

extern "C" void kernel_launch(void* const* d_in, const int* in_sizes, int n_in,
                              void* d_out, int out_size, void* d_ws, size_t ws_size,
                              hipStream_t stream) {
  (void)in_sizes; (void)n_in;
  const int* idx = (const int*)d_in[0];
  const void *emb = d_in[1], *wih_f = d_in[2], *whh_f = d_in[3];
  const void *bih_f = d_in[4], *bhh_f = d_in[5], *wih_b = d_in[6];
  const void *whh_b = d_in[7], *bih_b = d_in[8], *bhh_b = d_in[9];
  const void *linW = d_in[10], *linb = d_in[11];

  if (ws_size < (size_t)WS_NEED) {
    float v = -100.0f - (float)(unsigned)(ws_size >> 20);
    fallback_kernel<<<(out_size + 255) / 256, 256, 0, stream>>>((float*)d_out, out_size, v);
    return;
  }
  char* ws = (char*)d_ws;
  u32*   vote   = (u32*)(ws + OFF_VOTE);
  char*  hbuf2  = ws + OFF_HBUF;
  float* bias_n = (float*)(ws + OFF_BIAS);
  float* linb_n = (float*)(ws + OFF_LINB);
  u16*   linw_n = (u16*)(ws + OFF_LINW);
  u16*   whh_n  = (u16*)(ws + OFF_WHH);
  u16*   xs2    = (u16*)(ws + OFF_XS);
  u16*   wp2    = (u16*)(ws + OFF_WP);
  u16*   hs     = (u16*)(ws + OFF_HS);

  hipMemsetAsync(ws, 0, OFF_BIAS, stream);  // reset vote + exchange tags (re-run safe)
  prep_kernel<<<1079, 256, 0, stream>>>(idx, emb, wih_f, wih_b, whh_f, whh_b,
                                        bih_f, bih_b, bhh_f, bhh_b, linW, linb,
                                        xs2, wp2, whh_n, linw_n, bias_n, linb_n);
  scan_kernel<<<256, 256, 0, stream>>>(whh_n, bias_n, xs2, wp2, hbuf2, hs, vote);
  final_kernel<<<dim3(64, 4), 256, 0, stream>>>(hs, linw_n, linb_n, (float*)d_out);
}

// Round 4
// 1467.666 us; speedup vs baseline: 1.4671x; 1.3959x over previous
//
#include <hip/hip_runtime.h>

typedef unsigned short u16;
typedef unsigned int u32;
typedef unsigned long long u64;
typedef __attribute__((ext_vector_type(8))) short short8;    // 8 bf16 = 4 VGPRs (MFMA A/B frag)
typedef __attribute__((ext_vector_type(4))) float float4_;   // MFMA C/D frag
typedef __attribute__((ext_vector_type(4))) u16 ushort4_;    // 8B vector of bf16

#define SB 16384   // S*B
#define HH 512     // H
#define NC 21      // C+1

// ws layout (bytes). All offsets 16B-aligned.
#define OFF_VOTE 0u          // vote: [dir][64] u32 (slots 0..31, decision @32) (pad 4096)
#define OFF_FLG  4096u       // flags: [dir][32] u32 packed             (pad 4096) -> 8192
#define OFF_HBUF 8192u       // h dense dbuf [dir][parity][64][512]bf16 (262144) -> 270336
#define OFF_BIAS 270336u     // bias_n: [dir][4][512] f32               (16384)  -> 286720
#define OFF_LINB 286720u     // linb_n: 21 f32 (+pad)                   (256)    -> 286976
#define OFF_LINW 286976u     // linw_n: [21][1024] bf16                 (43008)  -> 329984
#define OFF_WHH  329984u     // whh_n: [dir*1536+row][512] bf16         (3145728)-> 3475712
#define OFF_XS   3475712u    // xs2 frag-packed: [s][4][10][512] bf16   (10485760)->13961472
#define OFF_WP   13961472u   // wp2 frag-packed: [192][10][512] bf16    (1966080)->15927552
#define OFF_HS   15927552u   // hs: [dir][SB][512] bf16                 (33554432)->49481984
#define WS_NEED  49481984u

__device__ __forceinline__ float b2f(u16 u) {
  union { u32 i; float f; } x; x.i = ((u32)u) << 16; return x.f;
}
__device__ __forceinline__ u16 f2b(float f) {  // RNE f32->bf16
  union { float f; u32 i; } x; x.f = f;
  u32 r = x.i + 0x7fffu + ((x.i >> 16) & 1u);
  return (u16)(r >> 16);
}
__device__ __forceinline__ float sigm(float x) { return 1.f / (1.f + __expf(-x)); }
__device__ __forceinline__ float tanh_f(float x) {
  x = fminf(fmaxf(x, -15.f), 15.f);
  float e = __expf(2.f * x);
  return (e - 1.f) / (e + 1.f);
}

// Runtime storage-dtype probe (kept from R6; cheap, in-bounds either way).
__device__ __forceinline__ bool detect_f32(const void* emb) {
  u16 v = ((const u16*)emb)[threadIdx.x & 63];
  int e = (v >> 7) & 0xff;
  return __ballot(e >= 147) != 0ull;
}
__device__ __forceinline__ float rdf(const void* p, size_t i, bool f32m) {
  return f32m ? ((const float*)p)[i] : b2f(((const u16*)p)[i]);
}

// ---- scoped memory ops. FULLSC=true: sc0 sc1 (MALL coherent point, mapping-free).
//      FULLSC=false: sc0 only (L1-bypass; served by this XCD's shared L2 — requires
//      all communicating blocks on one XCD, guaranteed by the startup vote). ----
template<bool FULLSC>
__device__ __forceinline__ u32 ld4(const void* p) {
  u32 r;
  if constexpr (FULLSC)
    asm volatile("global_load_dword %0, %1, off sc0 sc1" : "=v"(r) : "v"(p));
  else
    asm volatile("global_load_dword %0, %1, off sc0" : "=v"(r) : "v"(p));
  return r;
}
template<bool FULLSC>
__device__ __forceinline__ short8 ld16(const void* p) {
  short8 r;
  if constexpr (FULLSC)
    asm volatile("global_load_dwordx4 %0, %1, off sc0 sc1" : "=v"(r) : "v"(p));
  else
    asm volatile("global_load_dwordx4 %0, %1, off sc0" : "=v"(r) : "v"(p));
  return r;
}
template<bool FULLSC>
__device__ __forceinline__ void st4(void* p, u32 v) {
  if constexpr (FULLSC)
    asm volatile("global_store_dword %0, %1, off sc0 sc1" :: "v"(p), "v"(v) : "memory");
  else
    asm volatile("global_store_dword %0, %1, off sc0" :: "v"(p), "v"(v) : "memory");
}
template<bool FULLSC>
__device__ __forceinline__ void st8(void* p, u64 v) {
  if constexpr (FULLSC)
    asm volatile("global_store_dwordx2 %0, %1, off sc0 sc1" :: "v"(p), "v"(v) : "memory");
  else
    asm volatile("global_store_dwordx2 %0, %1, off sc0" :: "v"(p), "v"(v) : "memory");
}

__global__ __launch_bounds__(256) void fallback_kernel(float* out, int n, float v) {
  int i = blockIdx.x * 256 + threadIdx.x;
  if (i < n) out[i] = v;
}

// ---------------- normalize everything into canonical ws buffers (unchanged) ----------
__global__ __launch_bounds__(256) void prep_kernel(
    const int* __restrict__ idx, const void* __restrict__ emb,
    const void* __restrict__ wih_f, const void* __restrict__ wih_b,
    const void* __restrict__ whh_f, const void* __restrict__ whh_b,
    const void* __restrict__ bih_f, const void* __restrict__ bih_b,
    const void* __restrict__ bhh_f, const void* __restrict__ bhh_b,
    const void* __restrict__ linW, const void* __restrict__ linb,
    u16* __restrict__ xs2, u16* __restrict__ wp2, u16* __restrict__ whh_n,
    u16* __restrict__ linw_n, float* __restrict__ bias_n, float* __restrict__ linb_n) {
  bool f32m = detect_f32(emb);
  int tid = threadIdx.x, wid = tid >> 6, lane = tid & 63;
  int l15 = lane & 15, lq = lane >> 4;
  int blk = blockIdx.x;
  if (blk < 256) {                          // xs2[s][wid][ch][lane][8]
    int s = blk, b = wid * 16 + l15;
    size_t roff = (size_t)idx[b * 256 + s] * 300;
    u16* dst = xs2 + ((size_t)(s * 4 + wid) * 10) * 512 + lane * 8;
    #pragma unroll
    for (int ch = 0; ch < 10; ch++) {
      short8 v;
      #pragma unroll
      for (int j = 0; j < 8; j++) {
        int k = ch * 32 + lq * 8 + j;
        v[j] = (k < 300) ? (short)f2b(rdf(emb, roff + k, f32m)) : (short)0;
      }
      *(short8*)(dst + ch * 512) = v;
    }
  } else if (blk < 304) {                   // wp2[w=dir*96+slice*3+g][ch][lane][8]
    int w = (blk - 256) * 4 + wid;          // 0..191
    int dir = w / 96, rem = w - dir * 96;
    int slice = rem / 3, g = rem - slice * 3;
    const void* wp = dir ? wih_b : wih_f;
    size_t roff = (size_t)(g * 512 + slice * 16 + l15) * 300;
    u16* dst = wp2 + ((size_t)w * 10) * 512 + lane * 8;
    #pragma unroll
    for (int ch = 0; ch < 10; ch++) {
      short8 v;
      #pragma unroll
      for (int j = 0; j < 8; j++) {
        int k = ch * 32 + lq * 8 + j;
        v[j] = (k < 300) ? (short)f2b(rdf(wp, roff + k, f32m)) : (short)0;
      }
      *(short8*)(dst + ch * 512) = v;
    }
  } else if (blk < 1072) {                  // whh_n[dir*1536+rr][c]
    int row = (blk - 304) * 4 + wid;        // 0..3071
    int dir = (row >= 1536);
    int rr = row - dir * 1536;
    const void* p = dir ? whh_b : whh_f;
    u16* dst = whh_n + (size_t)row * 512;
    for (int c = lane; c < 512; c += 64)
      dst[c] = f2b(rdf(p, (size_t)rr * 512 + c, f32m));
  } else if (blk < 1078) {                  // linw_n[row][c], 21 rows x 1024
    int row = (blk - 1072) * 4 + wid;
    if (row < NC)
      for (int c = lane; c < 1024; c += 64)
        linw_n[(size_t)row * 1024 + c] = f2b(rdf(linW, (size_t)row * 1024 + c, f32m));
  } else {                                  // fused biases + linb (f32)
    for (int i = tid; i < 4096; i += 256) {
      int dir = i >> 11, vec = (i >> 9) & 3, u = i & 511;
      const void* bi = dir ? bih_b : bih_f;
      const void* bh = dir ? bhh_b : bhh_f;
      float v;
      if (vec == 0)      v = rdf(bi, u, f32m) + rdf(bh, u, f32m);
      else if (vec == 1) v = rdf(bi, 512 + u, f32m) + rdf(bh, 512 + u, f32m);
      else if (vec == 2) v = rdf(bi, 1024 + u, f32m);
      else               v = rdf(bh, 1024 + u, f32m);
      bias_n[i] = v;
    }
    for (int i = tid; i < NC; i += 256) linb_n[i] = rdf(linb, i, f32m);
  }
}

// ---------------- persistent bidirectional GRU scan -----------------------------------
// R10: flag protocol (R1, proven induction) + intra-XCD L2 placement (R9) + dense
// payload read exactly ONCE per step. R9's post-mortem: the tag-poll re-read the whole
// 24KB/wave exchange every retry — 10-15MB/step into ONE XCD's L2 (~4.3TB/s) = the
// 7us step, and the starvation caused the 1.5s outlier. Here the poll is a single
// 128B coalesced flag load per wave per retry (250x less), and the h payload (dense,
// no tags) is read once after the flags pass. Ordering within one L2 (fast) or the
// MALL (slow): h stores reach the serialization point (vmcnt drain before barrier),
// THEN the flag store; a reader that observes the flag and THEN issues h loads (all
// sc0/sc0sc1, L1-bypassed, volatile-asm-ordered) must see the h data.
// Overwrite-safety induction (R1): block X writes parity P=(t+1)&1 only after all
// flags >= t; flag_Y = t was stored after Y's step t-1 completed, whose h reads
// (from the same parity P) had returned before Y's barrier+flag. Monotonic flags;
// launch-time memset resets them.
// Protocol uniformity: a SINGLE decider wave (slice 0 of each dir) inspects the
// write-once XCC vote slots and publishes fast/slow to everyone — mixed-protocol
// divergence is structurally impossible.
template<bool FULLSC>
__device__ __forceinline__ void scan_loop(
    int dir, int slice, int j0, int tid, int wid, int lane, int l15, int lq,
    const u16 (*Wl)[520], const u16 (*Wx)[512], const float* bb,
    const u16* __restrict__ xs2, u16* __restrict__ hbuf, u16* __restrict__ hs,
    u32* __restrict__ flags) {
  float brz0[4], brz1[4], bin_[4], bhn_[4];
  #pragma unroll
  for (int r = 0; r < 4; r++) {
    int u = j0 + lq * 4 + r;
    brz0[r] = bb[u];
    brz1[r] = bb[512 + u];
    bin_[r] = bb[1024 + u];
    bhn_[r] = bb[1536 + u];
  }
  float hown[4] = {0.f, 0.f, 0.f, 0.f};     // private fp32 state: (b, j0+lq*4+r)
  int b = wid * 16 + l15;                   // this lane's batch row
  const size_t hs_dir = (size_t)dir * SB * HH;
  u32* fbase = flags + dir * 32;
  const u32* fl = fbase + (lane & 31);
  u32* selfflag = fbase + slice;

  for (int t = 0; t < 256; t++) {
    int s = dir ? (255 - t) : t;
    // ---- phase 1: input-gate MFMAs (weights from LDS; no h dependency) ----
    const u16* xbase = xs2 + ((size_t)(s * 4 + wid) * 10) * 512 + lane * 8;
    float4_ accr = (float4_)(0.f), accz = (float4_)(0.f);
    float4_ accni = (float4_)(0.f), accnh = (float4_)(0.f);
    short8 xf[10];
    #pragma unroll
    for (int ch = 0; ch < 10; ch++) xf[ch] = *(const short8*)(xbase + ch * 512);
    #pragma unroll
    for (int ch = 0; ch < 10; ch++) {
      short8 a0 = *(const short8*)&Wx[ch][lane * 8];
      short8 a1 = *(const short8*)&Wx[10 + ch][lane * 8];
      short8 a2 = *(const short8*)&Wx[20 + ch][lane * 8];
      accr  = __builtin_amdgcn_mfma_f32_16x16x32_bf16(a0, xf[ch], accr, 0, 0, 0);
      accz  = __builtin_amdgcn_mfma_f32_16x16x32_bf16(a1, xf[ch], accz, 0, 0, 0);
      accni = __builtin_amdgcn_mfma_f32_16x16x32_bf16(a2, xf[ch], accni, 0, 0, 0);
    }
    // ---- phase 2: cheap flag poll (128B coalesced per wave per retry) ----
    if (t > 0) {
      u32 target = (u32)t;
      long tries = 0;
      while (true) {
        u32 v = ld4<FULLSC>(fl);
        asm volatile("s_waitcnt vmcnt(0)" ::: "memory");
        __builtin_amdgcn_sched_barrier(0);
        if (__ballot(v >= target) == ~0ull) break;
        if (++tries > (1L << 22)) break;    // deadlock -> finite tripwire
        __builtin_amdgcn_s_sleep(1);
      }
      __asm__ volatile("" ::: "memory");
    }
    // ---- phase 3: dense h payload, read exactly once (16 x 16B per lane) ----
    const char* hrow = (const char*)hbuf +
        (((size_t)(dir * 2 + (t & 1)) * 64 + b) << 10) + lq * 16;
    short8 hf[16];
    #pragma unroll
    for (int k = 0; k < 16; k++) hf[k] = ld16<FULLSC>(hrow + k * 64);
    asm volatile("s_waitcnt vmcnt(0)" ::: "memory");
    __builtin_amdgcn_sched_barrier(0);      // keep MFMAs below the drain (rule #18)
    #pragma unroll
    for (int k = 0; k < 16; k++) {
      int kc = k * 32 + lq * 8;
      short8 a0 = *(const short8*)&Wl[l15][kc];
      short8 a1 = *(const short8*)&Wl[16 + l15][kc];
      short8 a2 = *(const short8*)&Wl[32 + l15][kc];
      accr  = __builtin_amdgcn_mfma_f32_16x16x32_bf16(a0, hf[k], accr, 0, 0, 0);
      accz  = __builtin_amdgcn_mfma_f32_16x16x32_bf16(a1, hf[k], accz, 0, 0, 0);
      accnh = __builtin_amdgcn_mfma_f32_16x16x32_bf16(a2, hf[k], accnh, 0, 0, 0);
    }
    // ---- phase 4: gates (f32), state update, publish ----
    union { ushort4_ v; u64 q; } ho;
    #pragma unroll
    for (int r = 0; r < 4; r++) {
      float rr = sigm(accr[r] + brz0[r]);
      float zz = sigm(accz[r] + brz1[r]);
      float nn = tanh_f(accni[r] + bin_[r] + rr * (accnh[r] + bhn_[r]));
      float hn = (1.f - zz) * nn + zz * hown[r];
      hown[r] = hn;
      ho.v[r] = f2b(hn);
    }
    char* hw = (char*)hbuf +
        (((size_t)(dir * 2 + ((t + 1) & 1)) * 64 + b) << 10) + (j0 + lq * 4) * 2;
    st8<FULLSC>(hw, ho.q);
    asm volatile("s_waitcnt vmcnt(0)" ::: "memory");  // h store acks at serialization pt
    __syncthreads();                                  // all 4 waves' stores drained
    if (tid == 0) st4<FULLSC>(selfflag, (u32)(t + 1));
    // hs trace store AFTER publish: off the critical path; kernel-end flush makes it
    // visible to final_kernel (separate dispatch, stream-ordered).
    *(ushort4_*)(hs + hs_dir + (size_t)(s * 64 + b) * HH + j0 + lq * 4) = ho.v;
  }
}

__global__ __launch_bounds__(256) void scan_kernel(
    const u16* __restrict__ whh_n, const float* __restrict__ bias_n,
    const u16* __restrict__ xs2, const u16* __restrict__ wp2,
    u16* __restrict__ hbuf, u16* __restrict__ hs,
    u32* __restrict__ vote, u32* __restrict__ flags) {
  __shared__ u16 Wl[48][520];               // 49,920 B
  __shared__ u16 Wx[30][512];               // 30,720 B (W_ih slice; kills per-step L2 reads)
  __shared__ u32 fast_sh;
  int wg = blockIdx.x;
  int xsel = wg & 7;
  if (xsel >= 2) return;                    // 192 idle blocks exit immediately
  int dir = xsel, slice = wg >> 3, j0 = slice * 16;
  int tid = threadIdx.x, wid = tid >> 6, lane = tid & 63;
  int l15 = lane & 15, lq = lane >> 4;

  // ---- startup vote: write-once XCC slot per block; one decider wave per dir ----
  u32* vd = vote + dir * 64;                // slots[32], decision @ [32]
  if (tid == 0) {
    u32 xcc = __builtin_amdgcn_s_getreg(63508);   // HW_REG_XCC_ID(20), off 0, sz 32
    st4<true>(vd + slice, (xcc & 31) + 1);
  }
  asm volatile("s_waitcnt vmcnt(0)" ::: "memory");
  if (slice == 0 && wid == 0) {             // decider: poll slots, publish decision
    u32 dec = 2;
    long it = 0;
    while (true) {
      u32 v = ld4<true>(vd + (lane & 31));
      asm volatile("s_waitcnt vmcnt(0)" ::: "memory");
      __builtin_amdgcn_sched_barrier(0);
      if (__ballot(v != 0) == ~0ull) {
        u32 v0 = (u32)__shfl((int)v, 0);
        dec = (__ballot(v == v0) == ~0ull) ? 1u : 2u;  // 1=fast(one XCD), 2=slow
        break;
      }
      if (++it > (1L << 22)) { dec = 2; break; }
      __builtin_amdgcn_s_sleep(2);
    }
    if (lane == 0) st4<true>(vd + 32, dec);
    asm volatile("s_waitcnt vmcnt(0)" ::: "memory");
  }

  // ---- stage W_hh slice and W_ih slice into LDS ----
  for (int q = tid; q < 48 * 256; q += 256) {
    int lr = q >> 8, qq = q & 255;
    int grp = lr >> 4, uu = lr & 15;
    const u32* srow = (const u32*)(whh_n + (size_t)(dir * 1536 + grp * 512 + j0 + uu) * 512);
    *(u32*)((char*)&Wl[lr][0] + qq * 4) = srow[qq];
  }
  {
    const u32* wsrc = (const u32*)(wp2 + ((size_t)(dir * 96 + slice * 3) * 10) * 512);
    for (int q = tid; q < 7680; q += 256) ((u32*)Wx)[q] = wsrc[q];
  }

  if (tid == 0) {                           // everyone adopts the decider's choice
    u32 d = 0;
    for (long it = 0; it < (1L << 24); ++it) {
      d = ld4<true>(vd + 32);
      asm volatile("s_waitcnt vmcnt(0)" ::: "memory");
      if (d) break;
      __builtin_amdgcn_s_sleep(2);
    }
    fast_sh = (d == 1) ? 1u : 0u;
  }
  __syncthreads();                          // Wl, Wx, fast_sh ready

  const float* bb = bias_n + dir * 2048;
  if (fast_sh)
    scan_loop<false>(dir, slice, j0, tid, wid, lane, l15, lq, Wl, Wx, bb,
                     xs2, hbuf, hs, flags);
  else
    scan_loop<true>(dir, slice, j0, tid, wid, lane, l15, lq, Wl, Wx, bb,
                    xs2, hbuf, hs, flags);
}

// ---------------- final: logits -> log_softmax -> out[B][21][S] (f32) (unchanged) -----
__global__ __launch_bounds__(256) void final_kernel(
    const u16* __restrict__ hs, const u16* __restrict__ linw_n,
    const float* __restrict__ linb_n, float* __restrict__ out) {
  __shared__ u16 Wl[NC][1032];
  __shared__ float lp[64][NC];
  __shared__ float lbs[NC];
  int tid = threadIdx.x, wid = tid >> 6, lane = tid & 63;
  int b = blockIdx.x, s0 = blockIdx.y * 64;
  for (int q = tid; q < NC * 512; q += 256) {
    int c = q >> 9, qq = q & 511;
    *(u32*)((char*)&Wl[c][0] + qq * 4) = ((const u32*)linw_n)[c * 512 + qq];
  }
  if (tid < NC) lbs[tid] = linb_n[tid];
  __syncthreads();
  #pragma unroll 1
  for (int i = 0; i < 16; i++) {
    int p = wid * 16 + i;
    int s = s0 + p;
    const u16* hfp = hs + (size_t)(s * 64 + b) * HH + lane * 8;
    const u16* hbp = hfp + (size_t)SB * HH;
    short8 va = *(const short8*)hfp;
    short8 vb = *(const short8*)hbp;
    float fa[8], fb[8];
    #pragma unroll
    for (int e = 0; e < 8; e++) { fa[e] = b2f((u16)va[e]); fb[e] = b2f((u16)vb[e]); }
    float mine = 0.f, mx = -1e30f;
    float lg[NC];
    #pragma unroll
    for (int c = 0; c < NC; c++) {
      short8 w1 = *(const short8*)((char*)&Wl[c][0] + lane * 16);
      short8 w2 = *(const short8*)((char*)&Wl[c][0] + 1024 + lane * 16);
      float ps = 0.f;
      #pragma unroll
      for (int e = 0; e < 8; e++)
        ps += fa[e] * b2f((u16)w1[e]) + fb[e] * b2f((u16)w2[e]);
      #pragma unroll
      for (int off = 32; off; off >>= 1) ps += __shfl_xor(ps, off);
      lg[c] = ps + lbs[c];
      mx = fmaxf(mx, lg[c]);
      if (lane == c) mine = lg[c];
    }
    float se = 0.f;
    #pragma unroll
    for (int c = 0; c < NC; c++) se += __expf(lg[c] - mx);
    float lse = mx + __logf(se);
    if (lane < NC) lp[p][lane] = mine - lse;
  }
  __syncthreads();
  for (int e = tid; e < NC * 64; e += 256) {
    int c = e >> 6, q = e & 63;
    out[((size_t)b * NC + c) * 256 + s0 + q] = lp[q][c];
  }
}

extern "C" void kernel_launch(void* const* d_in, const int* in_sizes, int n_in,
                              void* d_out, int out_size, void* d_ws, size_t ws_size,
                              hipStream_t stream) {
  (void)in_sizes; (void)n_in;
  const int* idx = (const int*)d_in[0];
  const void *emb = d_in[1], *wih_f = d_in[2], *whh_f = d_in[3];
  const void *bih_f = d_in[4], *bhh_f = d_in[5], *wih_b = d_in[6];
  const void *whh_b = d_in[7], *bih_b = d_in[8], *bhh_b = d_in[9];
  const void *linW = d_in[10], *linb = d_in[11];

  if (ws_size < (size_t)WS_NEED) {
    float v = -100.0f - (float)(unsigned)(ws_size >> 20);
    fallback_kernel<<<(out_size + 255) / 256, 256, 0, stream>>>((float*)d_out, out_size, v);
    return;
  }
  char* ws = (char*)d_ws;
  u32*   vote   = (u32*)(ws + OFF_VOTE);
  u32*   flags  = (u32*)(ws + OFF_FLG);
  u16*   hbuf   = (u16*)(ws + OFF_HBUF);
  float* bias_n = (float*)(ws + OFF_BIAS);
  float* linb_n = (float*)(ws + OFF_LINB);
  u16*   linw_n = (u16*)(ws + OFF_LINW);
  u16*   whh_n  = (u16*)(ws + OFF_WHH);
  u16*   xs2    = (u16*)(ws + OFF_XS);
  u16*   wp2    = (u16*)(ws + OFF_WP);
  u16*   hs     = (u16*)(ws + OFF_HS);

  hipMemsetAsync(ws, 0, OFF_BIAS, stream);  // reset vote + flags + h dbuf (re-run safe)
  prep_kernel<<<1079, 256, 0, stream>>>(idx, emb, wih_f, wih_b, whh_f, whh_b,
                                        bih_f, bih_b, bhh_f, bhh_b, linW, linb,
                                        xs2, wp2, whh_n, linw_n, bias_n, linb_n);
  scan_kernel<<<256, 256, 0, stream>>>(whh_n, bias_n, xs2, wp2, hbuf, hs, vote, flags);
  final_kernel<<<dim3(64, 4), 256, 0, stream>>>(hs, linw_n, linb_n, (float*)d_out);
}